// Round 8
// baseline (151.509 us; speedup 1.0000x reference)
//
#include <hip/hip_runtime.h>

#define H_IN 448
#define W_IN 448
#define HW_IN (H_IN * W_IN)
#define BGW 488
#define BGHW (BGW * BGW)
#define OUTI 256
#define OUTI_PIX (OUTI * OUTI)
#define OUTM 64
#define B_SAMPLES 64
#define BBOX_CHUNKS 16
#define BBOX_ROWS (H_IN / BBOX_CHUNKS)  // 28
#define BITS_STRIDE 8                    // u64 words per row
#define RPT 4                            // rows per thread in k_resize_img

typedef unsigned long long u64;

__device__ __forceinline__ float clamp01(float x) { return fminf(fmaxf(x, 0.f), 1.f); }
__device__ __forceinline__ int clampi(int x, int lo, int hi) { return min(max(x, lo), hi); }

// ---------------- K1: bbox + packed mask bitmask ----------------
__global__ void k_bbox(const float* __restrict__ ms, int* __restrict__ bbox,
                       u64* __restrict__ bits) {
    int b = blockIdx.y, chunk = blockIdx.x;
    int tid = threadIdx.x;
    int wave = tid >> 6, lane = tid & 63;
    const float* msB = ms + (size_t)b * HW_IN;
    u64* bitsB = bits + (size_t)b * H_IN * BITS_STRIDE;

    int miny = H_IN, maxy = -1, minx = W_IN, maxx = -1;
    for (int rr = wave; rr < BBOX_ROWS; rr += 4) {
        int row = chunk * BBOX_ROWS + rr;
        const float4* rowp = (const float4*)(msB + (size_t)row * W_IN);
#pragma unroll
        for (int sub = 0; sub < 2; ++sub) {
            int c4 = sub * 64 + lane;
            bool valid = c4 < (W_IN / 4);
            float4 v = rowp[min(c4, W_IN / 4 - 1)];
            bool a0 = valid && (v.x > 0.5f);
            bool a1 = valid && (v.y > 0.5f);
            bool a2 = valid && (v.z > 0.5f);
            bool a3 = valid && (v.w > 0.5f);
            u64 b0 = __ballot(a0), b1 = __ballot(a1), b2 = __ballot(a2), b3 = __ballot(a3);
            if (a0 | a1 | a2 | a3) {
                miny = min(miny, row); maxy = max(maxy, row);
                int xb = c4 * 4;
                if (a0) { minx = min(minx, xb);     maxx = max(maxx, xb); }
                if (a1) { minx = min(minx, xb + 1); maxx = max(maxx, xb + 1); }
                if (a2) { minx = min(minx, xb + 2); maxx = max(maxx, xb + 2); }
                if (a3) { minx = min(minx, xb + 3); maxx = max(maxx, xb + 3); }
            }
            if (lane < 4) {
                u64 w = (lane == 0) ? b0 : (lane == 1) ? b1 : (lane == 2) ? b2 : b3;
                bitsB[(size_t)row * BITS_STRIDE + sub * 4 + lane] = w;
            }
        }
    }
    __shared__ int s[4];
    if (tid == 0) { s[0] = H_IN; s[1] = -1; s[2] = W_IN; s[3] = -1; }
    __syncthreads();
    atomicMin(&s[0], miny); atomicMax(&s[1], maxy);
    atomicMin(&s[2], minx); atomicMax(&s[3], maxx);
    __syncthreads();
    if (tid == 0) {
        atomicMin(&bbox[b * 4 + 0], s[0]);
        atomicMin(&bbox[b * 4 + 1], -s[1]);
        atomicMin(&bbox[b * 4 + 2], s[2]);
        atomicMin(&bbox[b * 4 + 3], -s[3]);
    }
}

struct Geo {
    int miny, minx, h, w, top, left, Hp, Wp;
};
__device__ __forceinline__ Geo load_geo(const int* __restrict__ bbox,
                                        const int* __restrict__ pads, int b) {
    Geo g;
    g.miny = bbox[b * 4 + 0];
    int maxy = -bbox[b * 4 + 1];
    g.minx = bbox[b * 4 + 2];
    int maxx = -bbox[b * 4 + 3];
    int left = pads[b * 4 + 0], right = pads[b * 4 + 1];
    int top = pads[b * 4 + 2], bot = pads[b * 4 + 3];
    g.h = maxy - g.miny + 1;
    g.w = maxx - g.minx + 1;
    g.top = top; g.left = left;
    g.Hp = g.h + top + bot;
    g.Wp = g.w + left + right;
    return g;
}

__device__ __forceinline__ void src_coord(int i, int n_out, int size,
                                          int& t0, int& t1, float& frac) {
    float sizef = (float)size;
    float t = (i + 0.5f) * (sizef / (float)n_out) - 0.5f;
    t = fminf(fmaxf(t, 0.f), sizef - 1.f);
    t0 = (int)floorf(t);
    t1 = min(t0 + 1, size - 1);
    frac = t - (float)t0;
}

__device__ __forceinline__ bool mask_bit(const u64* rowbits, int c) {
    u64 w = rowbits[((c >> 8) << 2) | (c & 3)];
    return (w >> ((c >> 2) & 63)) & 1ULL;
}

// ---------------- K2: deep-MLP gather resize + brightness ----------------
// One thread = 4 output pixels (same column, 4 consecutive rows). ALL loads
// (48 img + 48 bg + 16 bit-words) issued via fully-unrolled static arrays before
// consumption. __launch_bounds__(256,1): let the allocator keep them in flight.
__global__ void __launch_bounds__(256, 1) k_resize_img(
        const float* __restrict__ img, const float* __restrict__ bg,
        const int* __restrict__ pads, const int* __restrict__ csel,
        const float* __restrict__ rcol, const float* __restrict__ jit,
        const int* __restrict__ bbox, const u64* __restrict__ bits,
        float* __restrict__ out, float* __restrict__ partials) {
    int oyBase = blockIdx.x * RPT;
    int b = blockIdx.y;
    int tid = threadIdx.x;

    Geo g = load_geo(bbox, pads, b);
    bool useBg = csel[b] > 2;
    float c0 = rcol[b * 3 + 0], c1 = rcol[b * 3 + 1], c2 = rcol[b * 3 + 2];
    float bfac = 0.9f + 0.2f * jit[b * 4 + 0];

    // column-side constants (shared across the 4 rows)
    int x0, x1; float wx;
    src_coord(tid, OUTI, g.Wp, x0, x1, wx);
    int cA = clampi(g.minx + x0 - g.left, 0, W_IN - 1);
    int cB = clampi(g.minx + x1 - g.left, 0, W_IN - 1);
    bool inxA = (x0 >= g.left) && (x0 < g.left + g.w);
    bool inxB = (x1 >= g.left) && (x1 < g.left + g.w);

    const float* imB = img + (size_t)b * 3 * HW_IN;
    const float* bgB = bg + (size_t)b * 3 * BGHW;
    const u64* bitsB = bits + (size_t)b * H_IN * BITS_STRIDE;

    // per-row geometry
    int y0v[RPT], y1v[RPT], r0v[RPT], r1v[RPT];
    float wyv[RPT];
    bool iy0[RPT], iy1[RPT];
#pragma unroll
    for (int rr = 0; rr < RPT; ++rr) {
        int y0, y1; float wy;
        src_coord(oyBase + rr, OUTI, g.Hp, y0, y1, wy);
        y0v[rr] = y0; y1v[rr] = y1; wyv[rr] = wy;
        r0v[rr] = clampi(g.miny + y0 - g.top, 0, H_IN - 1);
        r1v[rr] = clampi(g.miny + y1 - g.top, 0, H_IN - 1);
        iy0[rr] = (y0 >= g.top) && (y0 < g.top + g.h);
        iy1[rr] = (y1 >= g.top) && (y1 < g.top + g.h);
    }

    // mask bits: 4 rows x 4 taps (L2-resident bitmask)
    bool mm[RPT][4];
#pragma unroll
    for (int rr = 0; rr < RPT; ++rr) {
        mm[rr][0] = iy0[rr] && inxA && mask_bit(bitsB + (size_t)r0v[rr] * BITS_STRIDE, cA);
        mm[rr][1] = iy0[rr] && inxB && mask_bit(bitsB + (size_t)r0v[rr] * BITS_STRIDE, cB);
        mm[rr][2] = iy1[rr] && inxA && mask_bit(bitsB + (size_t)r1v[rr] * BITS_STRIDE, cA);
        mm[rr][3] = iy1[rr] && inxB && mask_bit(bitsB + (size_t)r1v[rr] * BITS_STRIDE, cB);
    }

    // img taps: 48 independent loads
    float iv[RPT][4][3];
#pragma unroll
    for (int rr = 0; rr < RPT; ++rr) {
#pragma unroll
        for (int tap = 0; tap < 4; ++tap) {
            int r = (tap & 2) ? r1v[rr] : r0v[rr];
            int c = (tap & 1) ? cB : cA;
            size_t off = (size_t)r * W_IN + c;
#pragma unroll
            for (int ch = 0; ch < 3; ++ch)
                iv[rr][tap][ch] = imB[(size_t)ch * HW_IN + off];
        }
    }

    // bg taps: 48 independent loads (block-uniform useBg)
    float bv[RPT][4][3];
    if (useBg) {
#pragma unroll
        for (int rr = 0; rr < RPT; ++rr) {
#pragma unroll
            for (int tap = 0; tap < 4; ++tap) {
                int P = (tap & 2) ? y1v[rr] : y0v[rr];     // <= Hp-1 <= 485 < 488
                int Q = (tap & 1) ? x1 : x0;               // <  Wp   <= 486 < 488
                size_t off = (size_t)P * BGW + Q;
#pragma unroll
                for (int ch = 0; ch < 3; ++ch)
                    bv[rr][tap][ch] = bgB[(size_t)ch * BGHW + off];
            }
        }
    } else {
#pragma unroll
        for (int rr = 0; rr < RPT; ++rr)
#pragma unroll
            for (int tap = 0; tap < 4; ++tap) {
                bv[rr][tap][0] = c0; bv[rr][tap][1] = c1; bv[rr][tap][2] = c2;
            }
    }

    // combine + store + gray accumulation
    float gacc = 0.f;
#pragma unroll
    for (int rr = 0; rr < RPT; ++rr) {
        float wy = wyv[rr];
        float w00 = (1.f - wy) * (1.f - wx);
        float w01 = (1.f - wy) * wx;
        float w10 = wy * (1.f - wx);
        float w11 = wy * wx;
        float o0 = w00 * (mm[rr][0] ? iv[rr][0][0] : bv[rr][0][0])
                 + w01 * (mm[rr][1] ? iv[rr][1][0] : bv[rr][1][0])
                 + w10 * (mm[rr][2] ? iv[rr][2][0] : bv[rr][2][0])
                 + w11 * (mm[rr][3] ? iv[rr][3][0] : bv[rr][3][0]);
        float o1 = w00 * (mm[rr][0] ? iv[rr][0][1] : bv[rr][0][1])
                 + w01 * (mm[rr][1] ? iv[rr][1][1] : bv[rr][1][1])
                 + w10 * (mm[rr][2] ? iv[rr][2][1] : bv[rr][2][1])
                 + w11 * (mm[rr][3] ? iv[rr][3][1] : bv[rr][3][1]);
        float o2 = w00 * (mm[rr][0] ? iv[rr][0][2] : bv[rr][0][2])
                 + w01 * (mm[rr][1] ? iv[rr][1][2] : bv[rr][1][2])
                 + w10 * (mm[rr][2] ? iv[rr][2][2] : bv[rr][2][2])
                 + w11 * (mm[rr][3] ? iv[rr][3][2] : bv[rr][3][2]);
        o0 = clamp01(o0 * bfac);
        o1 = clamp01(o1 * bfac);
        o2 = clamp01(o2 * bfac);
        size_t o = (size_t)b * 3 * OUTI_PIX + (size_t)(oyBase + rr) * OUTI + tid;
        out[o] = o0;
        out[o + OUTI_PIX] = o1;
        out[o + 2 * OUTI_PIX] = o2;
        gacc += 0.299f * o0 + 0.587f * o1 + 0.114f * o2;
    }

    // deterministic per-block (4-row) gray partial
#pragma unroll
    for (int off = 32; off > 0; off >>= 1) gacc += __shfl_down(gacc, off, 64);
    __shared__ float ls[4];
    int wid = tid >> 6, lane = tid & 63;
    if (lane == 0) ls[wid] = gacc;
    __syncthreads();
    if (tid == 0)
        partials[b * (OUTI / RPT) + blockIdx.x] = ls[0] + ls[1] + ls[2] + ls[3];
}

// ---------------- K2b: mask resize to 64x64 from the bitmask ----------------
__global__ void k_resize_msk(const u64* __restrict__ bits, const int* __restrict__ pads,
                             const int* __restrict__ bbox, float* __restrict__ outm) {
    int b = blockIdx.y;
    int pix = blockIdx.x * blockDim.x + threadIdx.x;  // 0..4095
    int oy = pix >> 6, ox = pix & 63;

    Geo g = load_geo(bbox, pads, b);
    int y0, y1, x0, x1; float wy, wx;
    src_coord(oy, OUTM, g.Hp, y0, y1, wy);
    src_coord(ox, OUTM, g.Wp, x0, x1, wx);

    const u64* bitsB = bits + (size_t)b * H_IN * BITS_STRIDE;
    float acc = 0.f;
#pragma unroll
    for (int tap = 0; tap < 4; ++tap) {
        int P = (tap & 2) ? y1 : y0;
        int Q = (tap & 1) ? x1 : x0;
        float wgt = ((tap & 2) ? wy : 1.f - wy) * ((tap & 1) ? wx : 1.f - wx);
        bool in_crop = (P >= g.top) && (P < g.top + g.h) && (Q >= g.left) && (Q < g.left + g.w);
        int r = clampi(g.miny + P - g.top, 0, H_IN - 1);
        int c = clampi(g.minx + Q - g.left, 0, W_IN - 1);
        bool mm = in_crop && mask_bit(bitsB + (size_t)r * BITS_STRIDE, c);
        acc += wgt * (mm ? 1.f : 0.f);
    }
    outm[(size_t)b * (OUTM * OUTM) + pix] = acc;
}

// ---------------- K3: contrast + saturation + hue jitter (in place, 4 px/thread) --------
__device__ __forceinline__ void jitter_px(float& r, float& g, float& bl,
                                          float cc, float ssf, float hd, float mean) {
    r = clamp01(cc * r + (1.f - cc) * mean);
    g = clamp01(cc * g + (1.f - cc) * mean);
    bl = clamp01(cc * bl + (1.f - cc) * mean);
    float gray = 0.299f * r + 0.587f * g + 0.114f * bl;
    r = clamp01(ssf * r + (1.f - ssf) * gray);
    g = clamp01(ssf * g + (1.f - ssf) * gray);
    bl = clamp01(ssf * bl + (1.f - ssf) * gray);
    float mx = fmaxf(r, fmaxf(g, bl));
    float mn = fminf(r, fminf(g, bl));
    float d = mx - mn;
    float dsv = (d > 0.f) ? d : 1.f;
    float hch;
    if (mx == r) {
        float t = (g - bl) / dsv;
        t = fmodf(t, 6.f);
        if (t < 0.f) t += 6.f;
        hch = t;
    } else if (mx == g) {
        hch = (bl - r) / dsv + 2.f;
    } else {
        hch = (r - g) / dsv + 4.f;
    }
    hch = (d > 0.f) ? hch * (1.f / 6.f) : 0.f;
    float sat = (mx > 0.f) ? d / mx : 0.f;
    float v = mx;
    float hh = hch + hd;
    hh -= floorf(hh);
    float h6 = hh * 6.f;
    float fi = floorf(h6);
    float f = h6 - fi;
    float pp = v * (1.f - sat);
    float q = v * (1.f - f * sat);
    float t = v * (1.f - (1.f - f) * sat);
    int im = ((int)fi) % 6;
    float ro, go, bo;
    switch (im) {
        case 0: ro = v;  go = t;  bo = pp; break;
        case 1: ro = q;  go = v;  bo = pp; break;
        case 2: ro = pp; go = v;  bo = t;  break;
        case 3: ro = pp; go = q;  bo = v;  break;
        case 4: ro = t;  go = pp; bo = v;  break;
        default: ro = v; go = pp; bo = q;  break;
    }
    r = clamp01(ro); g = clamp01(go); bl = clamp01(bo);
}

__global__ void k_jitter(float* __restrict__ io, const float* __restrict__ jit,
                         const float* __restrict__ partials) {
    int b = blockIdx.y;
    int tid = threadIdx.x;

    float pv = (tid < OUTI / RPT) ? partials[b * (OUTI / RPT) + tid] : 0.f;
#pragma unroll
    for (int off = 32; off > 0; off >>= 1) pv += __shfl_down(pv, off, 64);
    __shared__ float ls[4];
    int wid = tid >> 6, lane = tid & 63;
    if (lane == 0) ls[wid] = pv;
    __syncthreads();
    float mean = (ls[0] + ls[1] + ls[2] + ls[3]) * (1.f / (float)OUTI_PIX);

    float cc = 0.9f + 0.2f * jit[b * 4 + 1];
    float ssf = 0.9f + 0.2f * jit[b * 4 + 2];
    float hd = -0.1f + 0.2f * jit[b * 4 + 3];

    int idx4 = blockIdx.x * blockDim.x + tid;  // float4 index
    float4* pr = (float4*)(io + (size_t)b * 3 * OUTI_PIX) + idx4;
    float4* pg = pr + OUTI_PIX / 4;
    float4* pb = pr + 2 * (OUTI_PIX / 4);
    float4 r = *pr, g = *pg, bl = *pb;

    jitter_px(r.x, g.x, bl.x, cc, ssf, hd, mean);
    jitter_px(r.y, g.y, bl.y, cc, ssf, hd, mean);
    jitter_px(r.z, g.z, bl.z, cc, ssf, hd, mean);
    jitter_px(r.w, g.w, bl.w, cc, ssf, hd, mean);

    *pr = r; *pg = g; *pb = bl;
}

extern "C" void kernel_launch(void* const* d_in, const int* in_sizes, int n_in,
                              void* d_out, int out_size, void* d_ws, size_t ws_size,
                              hipStream_t stream) {
    const float* img = (const float*)d_in[0];
    const float* ms = (const float*)d_in[1];
    const float* bg = (const float*)d_in[2];
    const int* pads = (const int*)d_in[3];
    const int* csel = (const int*)d_in[4];
    const float* rcol = (const float*)d_in[5];
    const float* jit = (const float*)d_in[6];
    float* out = (float*)d_out;

    int* bbox = (int*)d_ws;                                        // 1 KB
    float* partials = (float*)((char*)d_ws + 1024);                // 64*64 f32 = 16 KB
    u64* bits = (u64*)((char*)d_ws + 1024 + B_SAMPLES * 64 * sizeof(float));  // 1.75 MB
    float* outm = out + (size_t)B_SAMPLES * 3 * OUTI_PIX;

    hipMemsetAsync(bbox, 0x7F, B_SAMPLES * 4 * sizeof(int), stream);

    k_bbox<<<dim3(BBOX_CHUNKS, B_SAMPLES), 256, 0, stream>>>(ms, bbox, bits);
    k_resize_img<<<dim3(OUTI / RPT, B_SAMPLES), 256, 0, stream>>>(
        img, bg, pads, csel, rcol, jit, bbox, bits, out, partials);
    k_resize_msk<<<dim3((OUTM * OUTM) / 256, B_SAMPLES), 256, 0, stream>>>(
        bits, pads, bbox, outm);
    k_jitter<<<dim3(OUTI_PIX / 4 / 256, B_SAMPLES), 256, 0, stream>>>(out, jit, partials);
}

// Round 9
// 122.440 us; speedup vs baseline: 1.2374x; 1.2374x over previous
//
#include <hip/hip_runtime.h>

#define H_IN 448
#define W_IN 448
#define HW_IN (H_IN * W_IN)
#define BGW 488
#define BGHW (BGW * BGW)
#define OUTI 256
#define OUTI_PIX (OUTI * OUTI)
#define OUTM 64
#define B_SAMPLES 64
#define BBOX_CHUNKS 16
#define BBOX_ROWS (H_IN / BBOX_CHUNKS)  // 28
#define BITS_STRIDE 8                    // u64 words per row

typedef unsigned long long u64;

__device__ __forceinline__ float clamp01(float x) { return fminf(fmaxf(x, 0.f), 1.f); }
__device__ __forceinline__ int clampi(int x, int lo, int hi) { return min(max(x, lo), hi); }

// async global->LDS 16B per lane: LDS dest = wave-uniform chunk base + lane*16,
// global src = per-lane address (m97/m104 contract).
__device__ __forceinline__ void gld_lds16(const float4* g, float4* l) {
    __builtin_amdgcn_global_load_lds(
        (const __attribute__((address_space(1))) void*)g,
        (__attribute__((address_space(3))) void*)l, 16, 0, 0);
}

// ---------------- K1: bbox + packed mask bitmask ----------------
__global__ void k_bbox(const float* __restrict__ ms, int* __restrict__ bbox,
                       u64* __restrict__ bits) {
    int b = blockIdx.y, chunk = blockIdx.x;
    int tid = threadIdx.x;
    int wave = tid >> 6, lane = tid & 63;
    const float* msB = ms + (size_t)b * HW_IN;
    u64* bitsB = bits + (size_t)b * H_IN * BITS_STRIDE;

    int miny = H_IN, maxy = -1, minx = W_IN, maxx = -1;
    for (int rr = wave; rr < BBOX_ROWS; rr += 4) {
        int row = chunk * BBOX_ROWS + rr;
        const float4* rowp = (const float4*)(msB + (size_t)row * W_IN);
#pragma unroll
        for (int sub = 0; sub < 2; ++sub) {
            int c4 = sub * 64 + lane;
            bool valid = c4 < (W_IN / 4);
            float4 v = rowp[min(c4, W_IN / 4 - 1)];
            bool a0 = valid && (v.x > 0.5f);
            bool a1 = valid && (v.y > 0.5f);
            bool a2 = valid && (v.z > 0.5f);
            bool a3 = valid && (v.w > 0.5f);
            u64 b0 = __ballot(a0), b1 = __ballot(a1), b2 = __ballot(a2), b3 = __ballot(a3);
            if (a0 | a1 | a2 | a3) {
                miny = min(miny, row); maxy = max(maxy, row);
                int xb = c4 * 4;
                if (a0) { minx = min(minx, xb);     maxx = max(maxx, xb); }
                if (a1) { minx = min(minx, xb + 1); maxx = max(maxx, xb + 1); }
                if (a2) { minx = min(minx, xb + 2); maxx = max(maxx, xb + 2); }
                if (a3) { minx = min(minx, xb + 3); maxx = max(maxx, xb + 3); }
            }
            if (lane < 4) {
                u64 w = (lane == 0) ? b0 : (lane == 1) ? b1 : (lane == 2) ? b2 : b3;
                bitsB[(size_t)row * BITS_STRIDE + sub * 4 + lane] = w;
            }
        }
    }
    __shared__ int s[4];
    if (tid == 0) { s[0] = H_IN; s[1] = -1; s[2] = W_IN; s[3] = -1; }
    __syncthreads();
    atomicMin(&s[0], miny); atomicMax(&s[1], maxy);
    atomicMin(&s[2], minx); atomicMax(&s[3], maxx);
    __syncthreads();
    if (tid == 0) {
        atomicMin(&bbox[b * 4 + 0], s[0]);
        atomicMin(&bbox[b * 4 + 1], -s[1]);
        atomicMin(&bbox[b * 4 + 2], s[2]);
        atomicMin(&bbox[b * 4 + 3], -s[3]);
    }
}

struct Geo {
    int miny, minx, h, w, top, left, Hp, Wp;
};
__device__ __forceinline__ Geo load_geo(const int* __restrict__ bbox,
                                        const int* __restrict__ pads, int b) {
    Geo g;
    g.miny = bbox[b * 4 + 0];
    int maxy = -bbox[b * 4 + 1];
    g.minx = bbox[b * 4 + 2];
    int maxx = -bbox[b * 4 + 3];
    int left = pads[b * 4 + 0], right = pads[b * 4 + 1];
    int top = pads[b * 4 + 2], bot = pads[b * 4 + 3];
    g.h = maxy - g.miny + 1;
    g.w = maxx - g.minx + 1;
    g.top = top; g.left = left;
    g.Hp = g.h + top + bot;
    g.Wp = g.w + left + right;
    return g;
}

__device__ __forceinline__ void src_coord(int i, int n_out, int size,
                                          int& t0, int& t1, float& frac) {
    float sizef = (float)size;
    float t = (i + 0.5f) * (sizef / (float)n_out) - 0.5f;
    t = fminf(fmaxf(t, 0.f), sizef - 1.f);
    t0 = (int)floorf(t);
    t1 = min(t0 + 1, size - 1);
    frac = t - (float)t0;
}

__device__ __forceinline__ bool mask_bit(const u64* rowbits, int c) {
    u64 w = rowbits[((c >> 8) << 2) | (c & 3)];
    return (w >> ((c >> 2) & 63)) & 1ULL;
}

// ---------------- K2: row-staged resize with ASYNC global_load_lds staging ----------------
// Block = one output row of one sample. img: 6 planes (2 rows x 3 ch) x 112 float4;
// bg: 6 planes x 122 float4 (only when useBg). Each wave issues its chunks async,
// one __syncthreads() drains. Then 4-tap bilinear composite from LDS.
__global__ void __launch_bounds__(256) k_resize_img(
        const float* __restrict__ img, const float* __restrict__ bg,
        const int* __restrict__ pads, const int* __restrict__ csel,
        const float* __restrict__ rcol, const float* __restrict__ jit,
        const int* __restrict__ bbox, const u64* __restrict__ bits,
        float* __restrict__ out, float* __restrict__ partials) {
    int oy = blockIdx.x;      // output row 0..255
    int b = blockIdx.y;       // sample
    int tid = threadIdx.x;    // output col 0..255
    int wave = tid >> 6, lane = tid & 63;

    Geo g = load_geo(bbox, pads, b);
    bool useBg = csel[b] > 2;
    float c0 = rcol[b * 3 + 0], c1 = rcol[b * 3 + 1], c2 = rcol[b * 3 + 2];
    float bfac = 0.9f + 0.2f * jit[b * 4 + 0];

    int y0, y1; float wy;
    src_coord(oy, OUTI, g.Hp, y0, y1, wy);
    int r0 = clampi(g.miny + y0 - g.top, 0, H_IN - 1);
    int r1 = clampi(g.miny + y1 - g.top, 0, H_IN - 1);
    bool incy0 = (y0 >= g.top) && (y0 < g.top + g.h);
    bool incy1 = (y1 >= g.top) && (y1 < g.top + g.h);

    __shared__ float s_im[6][W_IN];   // plane p = ky*3+ch... (p: 0,1,2=row r0 ch0..2; 3,4,5=row r1)
    __shared__ float s_bg[6][BGW];
    __shared__ u64 s_bits[2][BITS_STRIDE];
    __shared__ float ls[4];

    const float* imB = img + (size_t)b * 3 * HW_IN;
    const u64* bitsB = bits + (size_t)b * H_IN * BITS_STRIDE;

    // img staging: 12 chunks (6 planes x 2), wave w issues chunks {w, w+4, w+8}
#pragma unroll
    for (int k = 0; k < 3; ++k) {
        int item = wave + k * 4;          // 0..11
        int p = item >> 1;                // plane 0..5
        int ck = item & 1;                // chunk within plane
        int row = (p >= 3) ? r1 : r0;
        int ch = (p >= 3) ? (p - 3) : p;
        const float4* src =
            (const float4*)(imB + (size_t)ch * HW_IN + (size_t)row * W_IN) + ck * 64 + lane;
        float4* dst = (float4*)(&s_im[p][0]) + ck * 64;   // wave-uniform chunk base
        if (lane < (ck ? 48 : 64)) gld_lds16(src, dst);   // 64+48 = 112 float4
    }
    // bg staging: 12 chunks of 64/58 float4 (122 per plane), only when used
    if (useBg) {
        const float* bgB = bg + (size_t)b * 3 * BGHW;
#pragma unroll
        for (int k = 0; k < 3; ++k) {
            int item = wave + k * 4;
            int p = item >> 1;
            int ck = item & 1;
            int row = (p >= 3) ? y1 : y0;    // y0,y1 <= Hp-1 <= 485 < 488
            int ch = (p >= 3) ? (p - 3) : p;
            const float4* src =
                (const float4*)(bgB + (size_t)ch * BGHW + (size_t)row * BGW) + ck * 64 + lane;
            float4* dst = (float4*)(&s_bg[p][0]) + ck * 64;
            if (lane < (ck ? 58 : 64)) gld_lds16(src, dst);  // 64+58 = 122 float4
        }
    }
    // bits: 2 rows x 8 u64 (tiny, plain path)
    if (tid < 16) {
        int ky = tid >> 3, idx = tid & 7;
        s_bits[ky][idx] = bitsB[(size_t)(ky ? r1 : r0) * BITS_STRIDE + idx];
    }
    __syncthreads();   // drains vmcnt (incl. global_load_lds) + lgkm

    int x0, x1; float wx;
    src_coord(tid, OUTI, g.Wp, x0, x1, wx);

    float acc0 = 0.f, acc1 = 0.f, acc2 = 0.f;
#pragma unroll
    for (int tap = 0; tap < 4; ++tap) {
        int ky = tap >> 1;
        int ky3 = ky * 3;
        int Q = (tap & 1) ? x1 : x0;
        float wgt = (ky ? wy : 1.f - wy) * ((tap & 1) ? wx : 1.f - wx);
        bool incy = ky ? incy1 : incy0;
        bool in_crop = incy && (Q >= g.left) && (Q < g.left + g.w);
        int c = clampi(g.minx + Q - g.left, 0, W_IN - 1);
        bool mm = in_crop && mask_bit(s_bits[ky], c);
        float i0 = s_im[ky3 + 0][c], i1 = s_im[ky3 + 1][c], i2 = s_im[ky3 + 2][c];
        float b0, b1, b2;
        if (useBg) {   // block-uniform branch
            b0 = s_bg[ky3 + 0][Q]; b1 = s_bg[ky3 + 1][Q]; b2 = s_bg[ky3 + 2][Q];
        } else {
            b0 = c0; b1 = c1; b2 = c2;
        }
        acc0 += wgt * (mm ? i0 : b0);
        acc1 += wgt * (mm ? i1 : b1);
        acc2 += wgt * (mm ? i2 : b2);
    }
    float o0 = clamp01(acc0 * bfac);
    float o1 = clamp01(acc1 * bfac);
    float o2 = clamp01(acc2 * bfac);
    size_t o = (size_t)b * 3 * OUTI_PIX + (size_t)oy * OUTI + tid;
    out[o] = o0;
    out[o + OUTI_PIX] = o1;
    out[o + 2 * OUTI_PIX] = o2;

    // deterministic per-row gray partial sum
    float gsum = 0.299f * o0 + 0.587f * o1 + 0.114f * o2;
#pragma unroll
    for (int off = 32; off > 0; off >>= 1) gsum += __shfl_down(gsum, off, 64);
    int wid = tid >> 6, lane2 = tid & 63;
    if (lane2 == 0) ls[wid] = gsum;
    __syncthreads();
    if (tid == 0)
        partials[b * 256 + oy] = ls[0] + ls[1] + ls[2] + ls[3];
}

// ---------------- K2b: mask resize to 64x64 from the bitmask ----------------
__global__ void k_resize_msk(const u64* __restrict__ bits, const int* __restrict__ pads,
                             const int* __restrict__ bbox, float* __restrict__ outm) {
    int b = blockIdx.y;
    int pix = blockIdx.x * blockDim.x + threadIdx.x;  // 0..4095
    int oy = pix >> 6, ox = pix & 63;

    Geo g = load_geo(bbox, pads, b);
    int y0, y1, x0, x1; float wy, wx;
    src_coord(oy, OUTM, g.Hp, y0, y1, wy);
    src_coord(ox, OUTM, g.Wp, x0, x1, wx);

    const u64* bitsB = bits + (size_t)b * H_IN * BITS_STRIDE;
    float acc = 0.f;
#pragma unroll
    for (int tap = 0; tap < 4; ++tap) {
        int P = (tap & 2) ? y1 : y0;
        int Q = (tap & 1) ? x1 : x0;
        float wgt = ((tap & 2) ? wy : 1.f - wy) * ((tap & 1) ? wx : 1.f - wx);
        bool in_crop = (P >= g.top) && (P < g.top + g.h) && (Q >= g.left) && (Q < g.left + g.w);
        int r = clampi(g.miny + P - g.top, 0, H_IN - 1);
        int c = clampi(g.minx + Q - g.left, 0, W_IN - 1);
        bool mm = in_crop && mask_bit(bitsB + (size_t)r * BITS_STRIDE, c);
        acc += wgt * (mm ? 1.f : 0.f);
    }
    outm[(size_t)b * (OUTM * OUTM) + pix] = acc;
}

// ---------------- K3: contrast + saturation + hue jitter (in place, 4 px/thread) --------
__device__ __forceinline__ void jitter_px(float& r, float& g, float& bl,
                                          float cc, float ssf, float hd, float mean) {
    r = clamp01(cc * r + (1.f - cc) * mean);
    g = clamp01(cc * g + (1.f - cc) * mean);
    bl = clamp01(cc * bl + (1.f - cc) * mean);
    float gray = 0.299f * r + 0.587f * g + 0.114f * bl;
    r = clamp01(ssf * r + (1.f - ssf) * gray);
    g = clamp01(ssf * g + (1.f - ssf) * gray);
    bl = clamp01(ssf * bl + (1.f - ssf) * gray);
    float mx = fmaxf(r, fmaxf(g, bl));
    float mn = fminf(r, fminf(g, bl));
    float d = mx - mn;
    float dsv = (d > 0.f) ? d : 1.f;
    float hch;
    if (mx == r) {
        float t = (g - bl) / dsv;
        t = fmodf(t, 6.f);
        if (t < 0.f) t += 6.f;
        hch = t;
    } else if (mx == g) {
        hch = (bl - r) / dsv + 2.f;
    } else {
        hch = (r - g) / dsv + 4.f;
    }
    hch = (d > 0.f) ? hch * (1.f / 6.f) : 0.f;
    float sat = (mx > 0.f) ? d / mx : 0.f;
    float v = mx;
    float hh = hch + hd;
    hh -= floorf(hh);
    float h6 = hh * 6.f;
    float fi = floorf(h6);
    float f = h6 - fi;
    float pp = v * (1.f - sat);
    float q = v * (1.f - f * sat);
    float t = v * (1.f - (1.f - f) * sat);
    int im = ((int)fi) % 6;
    float ro, go, bo;
    switch (im) {
        case 0: ro = v;  go = t;  bo = pp; break;
        case 1: ro = q;  go = v;  bo = pp; break;
        case 2: ro = pp; go = v;  bo = t;  break;
        case 3: ro = pp; go = q;  bo = v;  break;
        case 4: ro = t;  go = pp; bo = v;  break;
        default: ro = v; go = pp; bo = q;  break;
    }
    r = clamp01(ro); g = clamp01(go); bl = clamp01(bo);
}

__global__ void k_jitter(float* __restrict__ io, const float* __restrict__ jit,
                         const float* __restrict__ partials) {
    int b = blockIdx.y;
    int tid = threadIdx.x;

    float pv = partials[b * 256 + tid];
#pragma unroll
    for (int off = 32; off > 0; off >>= 1) pv += __shfl_down(pv, off, 64);
    __shared__ float ls[4];
    int wid = tid >> 6, lane = tid & 63;
    if (lane == 0) ls[wid] = pv;
    __syncthreads();
    float mean = (ls[0] + ls[1] + ls[2] + ls[3]) * (1.f / (float)OUTI_PIX);

    float cc = 0.9f + 0.2f * jit[b * 4 + 1];
    float ssf = 0.9f + 0.2f * jit[b * 4 + 2];
    float hd = -0.1f + 0.2f * jit[b * 4 + 3];

    int idx4 = blockIdx.x * blockDim.x + tid;  // float4 index
    float4* pr = (float4*)(io + (size_t)b * 3 * OUTI_PIX) + idx4;
    float4* pg = pr + OUTI_PIX / 4;
    float4* pb = pr + 2 * (OUTI_PIX / 4);
    float4 r = *pr, g = *pg, bl = *pb;

    jitter_px(r.x, g.x, bl.x, cc, ssf, hd, mean);
    jitter_px(r.y, g.y, bl.y, cc, ssf, hd, mean);
    jitter_px(r.z, g.z, bl.z, cc, ssf, hd, mean);
    jitter_px(r.w, g.w, bl.w, cc, ssf, hd, mean);

    *pr = r; *pg = g; *pb = bl;
}

extern "C" void kernel_launch(void* const* d_in, const int* in_sizes, int n_in,
                              void* d_out, int out_size, void* d_ws, size_t ws_size,
                              hipStream_t stream) {
    const float* img = (const float*)d_in[0];
    const float* ms = (const float*)d_in[1];
    const float* bg = (const float*)d_in[2];
    const int* pads = (const int*)d_in[3];
    const int* csel = (const int*)d_in[4];
    const float* rcol = (const float*)d_in[5];
    const float* jit = (const float*)d_in[6];
    float* out = (float*)d_out;

    int* bbox = (int*)d_ws;                                        // 1 KB
    float* partials = (float*)((char*)d_ws + 1024);                // 64*256 f32 = 64 KB
    u64* bits = (u64*)((char*)d_ws + 1024 + B_SAMPLES * 256 * sizeof(float));  // 1.75 MB
    float* outm = out + (size_t)B_SAMPLES * 3 * OUTI_PIX;

    hipMemsetAsync(bbox, 0x7F, B_SAMPLES * 4 * sizeof(int), stream);

    k_bbox<<<dim3(BBOX_CHUNKS, B_SAMPLES), 256, 0, stream>>>(ms, bbox, bits);
    k_resize_img<<<dim3(OUTI, B_SAMPLES), 256, 0, stream>>>(
        img, bg, pads, csel, rcol, jit, bbox, bits, out, partials);
    k_resize_msk<<<dim3((OUTM * OUTM) / 256, B_SAMPLES), 256, 0, stream>>>(
        bits, pads, bbox, outm);
    k_jitter<<<dim3(OUTI_PIX / 4 / 256, B_SAMPLES), 256, 0, stream>>>(out, jit, partials);
}